// Round 19
// baseline (125.367 us; speedup 1.0000x reference)
//
#include <hip/hip_runtime.h>
#include <hip/hip_bf16.h>

typedef __attribute__((ext_vector_type(8))) short s16x8;
typedef __attribute__((ext_vector_type(16))) float f32x16;

__device__ __forceinline__ unsigned short f2bfu(float x) {
  __hip_bfloat16 b = __float2bfloat16(x);
  return *reinterpret_cast<unsigned short*>(&b);
}

// v_cvt_pk_bf16_f32: dst.lo16 = bf16(a), dst.hi16 = bf16(b)  (RNE)
__device__ __forceinline__ unsigned int cvtpk(float a, float b) {
  unsigned int r;
  asm("v_cvt_pk_bf16_f32 %0, %1, %2" : "=v"(r) : "v"(a), "v"(b));
  return r;
}

// ======== prep1: LDS-tiled packs (W2P, W1P, W3P) + per-row xw ========
// blocks 0..31: W2P; 32..47: W1P; 48..63: W3P; 64..319: xw rows (256)
__global__ __launch_bounds__(256) void prep1_k(
    const float* __restrict__ W2, const float* __restrict__ W3,
    const float* __restrict__ W1,
    unsigned short* __restrict__ W2P, unsigned short* __restrict__ W3P,
    unsigned short* __restrict__ W1P,
    const float* __restrict__ X0, const float* __restrict__ Wv,
    const float* __restrict__ Wq, const float* __restrict__ Wk,
    float* __restrict__ V0ws, float* __restrict__ QKws) {
  __shared__ __align__(16) char smc[65664];
  const int tid = threadIdx.x;
  const int blk = blockIdx.x;

  if (blk < 64) {  // packs: 32 k-rows per block, LDS transpose
    unsigned short* lt = (unsigned short*)smc;
    if (blk < 32) {  // ---- W2 [1024][512] -> W2P, pad 514 ----
      const int kb = blk;
#pragma unroll
      for (int i = 0; i < 16; ++i) {
        const int e4 = i * 256 + tid;
        const int r = e4 >> 7, c4 = (e4 & 127) * 4;
        const float4 v = *(const float4*)(W2 + (size_t)(kb * 32 + r) * 512 + c4);
        lt[r * 514 + c4 + 0] = f2bfu(v.x);
        lt[r * 514 + c4 + 1] = f2bfu(v.y);
        lt[r * 514 + c4 + 2] = f2bfu(v.z);
        lt[r * 514 + c4 + 3] = f2bfu(v.w);
      }
      __syncthreads();
#pragma unroll
      for (int i = 0; i < 8; ++i) {
        const int c = i * 256 + tid;
        const int kgl = c >> 10, nb = (c >> 6) & 15, l = c & 63;
        const int col = nb * 32 + (l & 31);
        const int k0 = kgl * 16 + (l >> 5) * 8;
        s16x8 v;
#pragma unroll
        for (int j = 0; j < 8; ++j) v[j] = lt[(k0 + j) * 514 + col];
        *(s16x8*)(W2P + ((size_t)((kb * 2 + kgl) * 16 + nb) * 64 + l) * 8) = v;
      }
    } else if (blk < 48) {  // ---- W1 [512][1024] -> W1P, pad 1026 ----
      const int kb = blk - 32;
#pragma unroll
      for (int i = 0; i < 32; ++i) {
        const int e4 = i * 256 + tid;
        const int r = e4 >> 8, c4 = (e4 & 255) * 4;
        const float4 v = *(const float4*)(W1 + (size_t)(kb * 32 + r) * 1024 + c4);
        lt[r * 1026 + c4 + 0] = f2bfu(v.x);
        lt[r * 1026 + c4 + 1] = f2bfu(v.y);
        lt[r * 1026 + c4 + 2] = f2bfu(v.z);
        lt[r * 1026 + c4 + 3] = f2bfu(v.w);
      }
      __syncthreads();
#pragma unroll
      for (int i = 0; i < 16; ++i) {
        const int c = i * 256 + tid;
        const int kgl = c >> 11, nb = (c >> 6) & 31, l = c & 63;
        const int col = nb * 32 + (l & 31);
        const int k0 = kgl * 16 + (l >> 5) * 8;
        s16x8 v;
#pragma unroll
        for (int j = 0; j < 8; ++j) v[j] = lt[(k0 + j) * 1026 + col];
        *(s16x8*)(W1P + ((size_t)((kb * 2 + kgl) * 32 + nb) * 64 + l) * 8) = v;
      }
    } else {  // ---- W3 [512][128] -> W3P, pad 130 ----
      const int kb = blk - 48;
#pragma unroll
      for (int i = 0; i < 4; ++i) {
        const int e4 = i * 256 + tid;
        const int r = e4 >> 5, c4 = (e4 & 31) * 4;
        const float4 v = *(const float4*)(W3 + (size_t)(kb * 32 + r) * 128 + c4);
        lt[r * 130 + c4 + 0] = f2bfu(v.x);
        lt[r * 130 + c4 + 1] = f2bfu(v.y);
        lt[r * 130 + c4 + 2] = f2bfu(v.z);
        lt[r * 130 + c4 + 3] = f2bfu(v.w);
      }
      __syncthreads();
#pragma unroll
      for (int i = 0; i < 2; ++i) {
        const int c = i * 256 + tid;
        const int kgl = c >> 8, nb = (c >> 6) & 3, l = c & 63;
        const int col = nb * 32 + (l & 31);
        const int k0 = kgl * 16 + (l >> 5) * 8;
        s16x8 v;
#pragma unroll
        for (int j = 0; j < 8; ++j) v[j] = lt[(k0 + j) * 130 + col];
        *(s16x8*)(W3P + ((size_t)((kb * 2 + kgl) * 4 + nb) * 64 + l) * 8) = v;
      }
    }
    return;
  }
  // ---- xw per-row: V0[row] = x0@Wv (512 cols), QK[row] = x0@[Wq|Wk] ----
  float* x0f = (float*)smc;
  const int row = blk - 64;
  x0f[tid] = X0[(size_t)row * 512 + tid];
  x0f[tid + 256] = X0[(size_t)row * 512 + 256 + tid];
  __syncthreads();
  {
    float a0 = 0, a1 = 0, b0 = 0, b1 = 0;
#pragma unroll 8
    for (int k = 0; k < 512; k += 2) {
      const float xv0 = x0f[k], xv1 = x0f[k + 1];
      a0 = fmaf(xv0, Wv[(size_t)k * 512 + tid], a0);
      b0 = fmaf(xv1, Wv[(size_t)(k + 1) * 512 + tid], b0);
      a1 = fmaf(xv0, Wv[(size_t)k * 512 + tid + 256], a1);
      b1 = fmaf(xv1, Wv[(size_t)(k + 1) * 512 + tid + 256], b1);
    }
    V0ws[(size_t)row * 512 + tid] = a0 + b0;
    V0ws[(size_t)row * 512 + tid + 256] = a1 + b1;
  }
  if (tid < 128) {
    const float* W = (tid < 64) ? Wq : Wk;
    const int j = tid & 63;
    float a = 0, bpart = 0;
#pragma unroll 8
    for (int k = 0; k < 512; k += 2) {
      a = fmaf(x0f[k], W[(size_t)k * 64 + j], a);
      bpart = fmaf(x0f[k + 1], W[(size_t)(k + 1) * 64 + j], bpart);
    }
    QKws[(size_t)row * 128 + tid] = a + bpart;
  }
}

// ======== prep2: wsm + C-row + prc (128 small MFMA blocks) ========
// blocks 0..255: wsm; 256..259: C; 260..387: prc
__global__ __launch_bounds__(256) void prep2_k(
    const float* __restrict__ Xs, const float* __restrict__ QKws,
    const float* __restrict__ bq, float* __restrict__ Wws,
    const float* __restrict__ V0ws, const float* __restrict__ X0,
    const float* __restrict__ bv, const float* __restrict__ W1,
    const unsigned short* __restrict__ W1P,
    const float* __restrict__ gp, const float* __restrict__ b1,
    float* __restrict__ Pws, float* __restrict__ Rws, float* __restrict__ Cws) {
  const int tid = threadIdx.x;
  if (blockIdx.x < 256) {  // wsm
    const int b = blockIdx.x, t = tid;
    __shared__ float sv[256];
    __shared__ float scal[4];
    sv[t] = (t == 0) ? 1.0f : Xs[b * 255 + t - 1];
    __syncthreads();
    if (t == 0) {
      float al = 0, g2 = 0;
      for (int j = 0; j < 64; ++j) {
        al = fmaf(QKws[b * 128 + j], QKws[b * 128 + 64 + j], al);
        g2 = fmaf(bq[j], QKws[b * 128 + 64 + j], g2);
      }
      float mx = sv[0], mn = sv[0];
      for (int m2 = 1; m2 < 256; ++m2) { mx = fmaxf(mx, sv[m2]); mn = fminf(mn, sv[m2]); }
      scal[0] = al; scal[1] = g2; scal[2] = mx; scal[3] = mn;
    }
    __syncthreads();
    const float c = fmaf(scal[0], sv[tid], scal[1]);
    const float M = (c >= 0.f) ? c * scal[2] : c * scal[3];
    float Z = 0, Wm = 0;
    for (int m2 = 0; m2 < 256; ++m2) {
      const float e = __expf(fmaf(c, sv[m2], -M));
      Z += e;
      Wm = fmaf(sv[m2], e, Wm);
    }
    Wws[b * 256 + tid] = Wm / Z;
    return;
  }
  if (blockIdx.x < 260) {  // C[col] = g*(bv@W1)[col] + b1[col]
    const int col = (blockIdx.x - 256) * 256 + tid;
    float a = 0;
    for (int d = 0; d < 512; ++d) a = fmaf(bv[d], W1[(size_t)d * 1024 + col], a);
    Cws[col] = fmaf(gp[0], a, b1[col]);
    return;
  }
  // prc: {P,R} = {V0,X0} @ W1 (bf16 MFMA), 64x64 tile per block, 4 waves
  const int r = blockIdx.x - 260;        // 0..127
  const int pr = r >> 6;                 // 0: P(V0), 1: R(X0)
  const int rem = r & 63;
  const int mb = rem >> 4, nb = rem & 15;
  const float* srcA = pr ? X0 : V0ws;
  float* dst = pr ? Rws : Pws;
  const int lane = tid & 63, w = tid >> 6;
  const int la31 = lane & 31, hi = lane >> 5;
  const int rowbase = mb * 64 + (w >> 1) * 32;
  const int nbW = nb * 2 + (w & 1);
  const float* ar = srcA + (size_t)(rowbase + la31) * 512 + hi * 8;
  const unsigned short* pBW = W1P + ((size_t)nbW * 64 + lane) * 8;  // +16384/kg

  f32x16 acc;
#pragma unroll
  for (int i = 0; i < 16; ++i) acc[i] = 0.f;

  float4 fa[2][2];
  s16x8 bst[2];
  fa[0][0] = *(const float4*)(ar);
  fa[0][1] = *(const float4*)(ar + 4);
  bst[0] = *(const s16x8*)(pBW);
  pBW += 16384;

#pragma unroll 2
  for (int kg = 0; kg < 32; ++kg) {
    const int par = kg & 1;
    if (kg < 31) {
      fa[par ^ 1][0] = *(const float4*)(ar + (kg + 1) * 16);
      fa[par ^ 1][1] = *(const float4*)(ar + (kg + 1) * 16 + 4);
      bst[par ^ 1] = *(const s16x8*)(pBW);
      pBW += 16384;
    }
    union { s16x8 v; unsigned int u[4]; } t;
    const float4 a0 = fa[par][0], a1 = fa[par][1];
    t.u[0] = cvtpk(a0.x, a0.y);
    t.u[1] = cvtpk(a0.z, a0.w);
    t.u[2] = cvtpk(a1.x, a1.y);
    t.u[3] = cvtpk(a1.z, a1.w);
    acc = __builtin_amdgcn_mfma_f32_32x32x16_bf16(t.v, bst[par], acc, 0, 0, 0);
  }
#pragma unroll
  for (int reg = 0; reg < 16; ++reg) {
    const int rowl = (reg & 3) + 8 * (reg >> 2) + 4 * hi;
    dst[(size_t)(rowbase + rowl) * 1024 + nbW * 32 + la31] = acc[reg];
  }
}

// ======== fused: out = relu(relu(h1@W2+b2)@W3 + b3) ========
// BM=128, grid 512, 1024 thr (16 waves), phase A 1m x 16n: wave tile 128x32
// (acc 4x f32x16 = 64 AGPR), ZERO B dup -> block B traffic 1MB (total 512MB,
// half of R18). A-tile gen'd once/block into LDS dbuf (16 elems/thread,
// k-oct tid>>7 wave-uniform). B ring-of-4 depth-3 prefetch + setprio.
// LDS: At dbuf 2x32KB [0,65536) + PRC 12KB [65536,77824) phase A;
//      h2t 128KB [0,131072) phase B. 1 block/CU, 4 waves/SIMD.
__global__ __launch_bounds__(1024, 4) void fused_k(
    const float* __restrict__ Xs, const float* __restrict__ gp,
    const unsigned short* __restrict__ W2P,  // packed, 1MB
    const float* __restrict__ b2,
    const unsigned short* __restrict__ W3P,  // packed, 128KB
    const float* __restrict__ b3,
    const float* __restrict__ Cws, const float* __restrict__ Wws,
    const float* __restrict__ Pws, const float* __restrict__ Rws,
    float* __restrict__ out)  // [65536][128] f32
{
  __shared__ __align__(16) unsigned char sm[131072];
  unsigned short* smU = (unsigned short*)sm;
  float* PRC = (float*)(sm + 65536);  // P[1024] | R[1024] | C[1024]
  const int tid = threadIdx.x;
  const int lane = tid & 63, wid = tid >> 6;  // wid 0..15 = column group
  const int la31 = lane & 31, hi = lane >> 5;
  const int m0 = blockIdx.x * 128;
  const int b = blockIdx.x >> 1;
  const float g = gp[0];

  // A-generation: thread -> row rg 0..127; k-oct pair {ko, ko+8}, ko=tid>>7
  const int rg = tid & 127;
  const int ko = tid >> 7;  // wave-uniform (= wid>>1)
  const int tokg = (m0 & 255) + rg;
  const float gw = g * Wws[b * 256 + tokg];
  const float sr = (tokg == 0) ? 1.0f : Xs[b * 255 + tokg - 1];

  // PRC -> LDS: 3 elems/thread
#pragma unroll
  for (int i = 0; i < 3; ++i) {
    const int idx = i * 1024 + tid;
    float v;
    if (idx < 1024)      v = Pws[b * 1024 + idx];
    else if (idx < 2048) v = Rws[b * 1024 + (idx - 1024)];
    else                 v = Cws[idx - 2048];
    PRC[idx] = v;
  }

  // generate A-tile for `step` (128 rows x BK=128) into buffer `buf`
  auto gen = [&](int buf, int step) {
#pragma unroll
    for (int gsub = 0; gsub < 2; ++gsub) {
      const int s = gsub * 8 + ko;               // k-oct 0..15
      const int kb = step * 128 + s * 8;
      float e[8];
#pragma unroll
      for (int j = 0; j < 8; j += 4) {
        const float4 Pv = *(const float4*)(PRC + kb + j);          // broadcast
        const float4 Rv = *(const float4*)(PRC + 1024 + kb + j);
        const float4 Cv = *(const float4*)(PRC + 2048 + kb + j);
        e[j + 0] = fmaxf(fmaf(gw, Pv.x, fmaf(sr, Rv.x, Cv.x)), 0.f);
        e[j + 1] = fmaxf(fmaf(gw, Pv.y, fmaf(sr, Rv.y, Cv.y)), 0.f);
        e[j + 2] = fmaxf(fmaf(gw, Pv.z, fmaf(sr, Rv.z, Cv.z)), 0.f);
        e[j + 3] = fmaxf(fmaf(gw, Pv.w, fmaf(sr, Rv.w, Cv.w)), 0.f);
      }
      union { s16x8 v; unsigned int u[4]; } t0;
      t0.u[0] = cvtpk(e[0], e[1]);  t0.u[1] = cvtpk(e[2], e[3]);
      t0.u[2] = cvtpk(e[4], e[5]);  t0.u[3] = cvtpk(e[6], e[7]);
      *(s16x8*)(sm + buf * 32768 + (s * 128 + rg) * 16) = t0.v;
    }
  };

  f32x16 acc[4];
#pragma unroll
  for (int mf = 0; mf < 4; ++mf)
#pragma unroll
    for (int i = 0; i < 16; ++i) acc[mf][i] = 0.f;

  // B: ring-of-4 prefetch depth 3; wave wid owns frag nb=wid; +8192 elems/kg
  const unsigned short* pB = W2P + ((size_t)wid * 64 + lane) * 8;
  s16x8 bst[4];
#pragma unroll
  for (int d = 0; d < 3; ++d) {
    bst[d] = *(const s16x8*)(pB);
    pB += 8192;
  }

  __syncthreads();     // PRC ready
  gen(0, 0);           // prologue A-tile

  // ---- phase A: 8 steps x 8 kg, 1 barrier/step, B 3-deep in flight ----
  int kg = 0;
  for (int step = 0; step < 8; ++step) {
    __syncthreads();   // buf[step&1] visible; other buf free to write
    if (step < 7) gen((step + 1) & 1, step + 1);
    const int abase = (step & 1) * 32768;
#pragma unroll
    for (int kgl = 0; kgl < 8; ++kgl, ++kg) {
      bst[(kg + 3) & 3] = *(const s16x8*)(pB);  // tail lands in W3P — safe
      pB += 8192;
      s16x8 af[4];
#pragma unroll
      for (int mf = 0; mf < 4; ++mf)
        af[mf] = *(const s16x8*)(sm + abase + ((kgl * 2 + hi) * 128 + mf * 32 + la31) * 16);
      const int cur = kg & 3;
      __builtin_amdgcn_s_setprio(1);
#pragma unroll
      for (int mf = 0; mf < 4; ++mf)
        acc[mf] = __builtin_amdgcn_mfma_f32_32x32x16_bf16(af[mf], bst[cur], acc[mf], 0, 0, 0);
      __builtin_amdgcn_s_setprio(0);
    }
  }
  __syncthreads();  // last A-reads done before h2t overwrites LDS

  // ---- transition: h2 (bias+relu, bf16) -> h2t swizzled (128 rows) ----
  {
    const int col = wid * 32 + la31;
    const float bb = b2[col];
    const int sc = col >> 3, c7 = col & 7;
#pragma unroll
    for (int mf = 0; mf < 4; ++mf) {
#pragma unroll
      for (int reg = 0; reg < 16; ++reg) {
        const int row = mf * 32 + (reg & 3) + 8 * (reg >> 2) + 4 * hi;
        const int sp = (sc & 56) | ((sc ^ row) & 7);
        smU[row * 512 + sp * 8 + c7] = f2bfu(fmaxf(acc[mf][reg] + bb, 0.f));
      }
    }
  }
  __syncthreads();  // h2t ready

  // ---- phase B: out 128x128 = relu(h2t @ W3 + b3); 16 waves 4m x 4n ----
  const int wr = wid >> 2, wc = wid & 3;
  f32x16 acc2;
#pragma unroll
  for (int i = 0; i < 16; ++i) acc2[i] = 0.f;

  const unsigned short* pW = W3P + ((size_t)wc * 64 + lane) * 8;  // +2048/kg
  s16x8 wst[4];
#pragma unroll
  for (int d = 0; d < 3; ++d) {
    wst[d] = *(const s16x8*)(pW);
    pW += 2048;
  }
#pragma unroll 4
  for (int kg2 = 0; kg2 < 32; ++kg2) {
    wst[(kg2 + 3) & 3] = *(const s16x8*)(pW);  // tail lands in V0ws — safe
    pW += 2048;
    const int s = kg2 * 2 + hi;
    const int row = wr * 32 + la31;
    const int sp = (s & 56) | ((s ^ row) & 7);
    const s16x8 afh = *(const s16x8*)(&sm[row * 1024 + (sp << 4)]);
    __builtin_amdgcn_s_setprio(1);
    acc2 = __builtin_amdgcn_mfma_f32_32x32x16_bf16(afh, wst[kg2 & 3], acc2, 0, 0, 0);
    __builtin_amdgcn_s_setprio(0);
  }

  // ---- epilogue: direct coalesced f32 stores ----
  {
    const int cB = wc * 32 + la31;
    const float b3v = b3[cB];
#pragma unroll
    for (int reg = 0; reg < 16; ++reg) {
      const int row = m0 + wr * 32 + (reg & 3) + 8 * (reg >> 2) + 4 * hi;
      out[(size_t)row * 128 + cB] = fmaxf(acc2[reg] + b3v, 0.f);
    }
  }
}

extern "C" void kernel_launch(void* const* d_in, const int* in_sizes, int n_in,
                              void* d_out, int out_size, void* d_ws, size_t ws_size,
                              hipStream_t stream) {
  const float* X0 = (const float*)d_in[0];
  const float* Xs = (const float*)d_in[1];
  const float* Wq = (const float*)d_in[2];
  const float* bq = (const float*)d_in[3];
  const float* Wk = (const float*)d_in[4];
  const float* bk = (const float*)d_in[5];
  const float* Wv = (const float*)d_in[6];
  const float* bv = (const float*)d_in[7];
  const float* gp = (const float*)d_in[8];
  const float* W1 = (const float*)d_in[9];
  const float* b1 = (const float*)d_in[10];
  const float* W2 = (const float*)d_in[11];
  const float* b2 = (const float*)d_in[12];
  const float* W3 = (const float*)d_in[13];
  const float* b3 = (const float*)d_in[14];

  char* ws = (char*)d_ws;
  float* Cws = (float*)(ws);                              //   4 KB
  float* Wws = (float*)(ws + 4096);                       // 256 KB
  float* Pws = (float*)(ws + 266240);                     //   1 MB
  float* Rws = (float*)(ws + 1314816);                    //   1 MB
  unsigned short* W2P = (unsigned short*)(ws + 2363392);  //   1 MB (packed bf16)
  unsigned short* W3P = (unsigned short*)(ws + 3411968);  // 128 KB (packed bf16)
  float* V0ws = (float*)(ws + 3543040);                   // 512 KB
  float* QKws = (float*)(ws + 4067328);                   // 128 KB
  unsigned short* W1P = (unsigned short*)(ws + 4198400);  //   1 MB (packed bf16)
  float* out = (float*)d_out;

  hipLaunchKernelGGL(prep1_k, dim3(320), dim3(256), 0, stream,
                     W2, W3, W1, W2P, W3P, W1P, X0, Wv, Wq, Wk, V0ws, QKws);
  hipLaunchKernelGGL(prep2_k, dim3(388), dim3(256), 0, stream,
                     Xs, QKws, bq, Wws, V0ws, X0, bv, W1, W1P, gp, b1, Pws, Rws, Cws);
  hipLaunchKernelGGL(fused_k, dim3(512), dim3(1024), 0, stream,
                     Xs, gp, W2P, b2, W3P, b3, Cws, Wws, Pws, Rws, out);
}

// Round 20
// 125.002 us; speedup vs baseline: 1.0029x; 1.0029x over previous
//
#include <hip/hip_runtime.h>
#include <hip/hip_bf16.h>

typedef __attribute__((ext_vector_type(8))) short s16x8;
typedef __attribute__((ext_vector_type(16))) float f32x16;

__device__ __forceinline__ unsigned short f2bfu(float x) {
  __hip_bfloat16 b = __float2bfloat16(x);
  return *reinterpret_cast<unsigned short*>(&b);
}

// v_cvt_pk_bf16_f32: dst.lo16 = bf16(a), dst.hi16 = bf16(b)  (RNE)
__device__ __forceinline__ unsigned int cvtpk(float a, float b) {
  unsigned int r;
  asm("v_cvt_pk_bf16_f32 %0, %1, %2" : "=v"(r) : "v"(a), "v"(b));
  return r;
}

// Barrier that orders LDS (lgkmcnt) but does NOT drain vmcnt — keeps the
// global-load prefetch ring in flight across step boundaries (T4).
__device__ __forceinline__ void softBarrier() {
  asm volatile("s_waitcnt lgkmcnt(0)" ::: "memory");
  __builtin_amdgcn_sched_barrier(0);
  __builtin_amdgcn_s_barrier();
  __builtin_amdgcn_sched_barrier(0);
}

// ======== prep1: LDS-tiled packs (W2P, W1P, W3P) + per-row xw ========
// blocks 0..31: W2P; 32..47: W1P; 48..63: W3P; 64..319: xw rows (256)
__global__ __launch_bounds__(256) void prep1_k(
    const float* __restrict__ W2, const float* __restrict__ W3,
    const float* __restrict__ W1,
    unsigned short* __restrict__ W2P, unsigned short* __restrict__ W3P,
    unsigned short* __restrict__ W1P,
    const float* __restrict__ X0, const float* __restrict__ Wv,
    const float* __restrict__ Wq, const float* __restrict__ Wk,
    float* __restrict__ V0ws, float* __restrict__ QKws) {
  __shared__ __align__(16) char smc[65664];
  const int tid = threadIdx.x;
  const int blk = blockIdx.x;

  if (blk < 64) {  // packs: 32 k-rows per block, LDS transpose
    unsigned short* lt = (unsigned short*)smc;
    if (blk < 32) {  // ---- W2 [1024][512] -> W2P, pad 514 ----
      const int kb = blk;
#pragma unroll
      for (int i = 0; i < 16; ++i) {
        const int e4 = i * 256 + tid;
        const int r = e4 >> 7, c4 = (e4 & 127) * 4;
        const float4 v = *(const float4*)(W2 + (size_t)(kb * 32 + r) * 512 + c4);
        lt[r * 514 + c4 + 0] = f2bfu(v.x);
        lt[r * 514 + c4 + 1] = f2bfu(v.y);
        lt[r * 514 + c4 + 2] = f2bfu(v.z);
        lt[r * 514 + c4 + 3] = f2bfu(v.w);
      }
      __syncthreads();
#pragma unroll
      for (int i = 0; i < 8; ++i) {
        const int c = i * 256 + tid;
        const int kgl = c >> 10, nb = (c >> 6) & 15, l = c & 63;
        const int col = nb * 32 + (l & 31);
        const int k0 = kgl * 16 + (l >> 5) * 8;
        s16x8 v;
#pragma unroll
        for (int j = 0; j < 8; ++j) v[j] = lt[(k0 + j) * 514 + col];
        *(s16x8*)(W2P + ((size_t)((kb * 2 + kgl) * 16 + nb) * 64 + l) * 8) = v;
      }
    } else if (blk < 48) {  // ---- W1 [512][1024] -> W1P, pad 1026 ----
      const int kb = blk - 32;
#pragma unroll
      for (int i = 0; i < 32; ++i) {
        const int e4 = i * 256 + tid;
        const int r = e4 >> 8, c4 = (e4 & 255) * 4;
        const float4 v = *(const float4*)(W1 + (size_t)(kb * 32 + r) * 1024 + c4);
        lt[r * 1026 + c4 + 0] = f2bfu(v.x);
        lt[r * 1026 + c4 + 1] = f2bfu(v.y);
        lt[r * 1026 + c4 + 2] = f2bfu(v.z);
        lt[r * 1026 + c4 + 3] = f2bfu(v.w);
      }
      __syncthreads();
#pragma unroll
      for (int i = 0; i < 16; ++i) {
        const int c = i * 256 + tid;
        const int kgl = c >> 11, nb = (c >> 6) & 31, l = c & 63;
        const int col = nb * 32 + (l & 31);
        const int k0 = kgl * 16 + (l >> 5) * 8;
        s16x8 v;
#pragma unroll
        for (int j = 0; j < 8; ++j) v[j] = lt[(k0 + j) * 1026 + col];
        *(s16x8*)(W1P + ((size_t)((kb * 2 + kgl) * 32 + nb) * 64 + l) * 8) = v;
      }
    } else {  // ---- W3 [512][128] -> W3P, pad 130 ----
      const int kb = blk - 48;
#pragma unroll
      for (int i = 0; i < 4; ++i) {
        const int e4 = i * 256 + tid;
        const int r = e4 >> 5, c4 = (e4 & 31) * 4;
        const float4 v = *(const float4*)(W3 + (size_t)(kb * 32 + r) * 128 + c4);
        lt[r * 130 + c4 + 0] = f2bfu(v.x);
        lt[r * 130 + c4 + 1] = f2bfu(v.y);
        lt[r * 130 + c4 + 2] = f2bfu(v.z);
        lt[r * 130 + c4 + 3] = f2bfu(v.w);
      }
      __syncthreads();
#pragma unroll
      for (int i = 0; i < 2; ++i) {
        const int c = i * 256 + tid;
        const int kgl = c >> 8, nb = (c >> 6) & 3, l = c & 63;
        const int col = nb * 32 + (l & 31);
        const int k0 = kgl * 16 + (l >> 5) * 8;
        s16x8 v;
#pragma unroll
        for (int j = 0; j < 8; ++j) v[j] = lt[(k0 + j) * 130 + col];
        *(s16x8*)(W3P + ((size_t)((kb * 2 + kgl) * 4 + nb) * 64 + l) * 8) = v;
      }
    }
    return;
  }
  // ---- xw per-row: V0[row] = x0@Wv (512 cols), QK[row] = x0@[Wq|Wk] ----
  float* x0f = (float*)smc;
  const int row = blk - 64;
  x0f[tid] = X0[(size_t)row * 512 + tid];
  x0f[tid + 256] = X0[(size_t)row * 512 + 256 + tid];
  __syncthreads();
  {
    float a0 = 0, a1 = 0, b0 = 0, b1 = 0;
#pragma unroll 8
    for (int k = 0; k < 512; k += 2) {
      const float xv0 = x0f[k], xv1 = x0f[k + 1];
      a0 = fmaf(xv0, Wv[(size_t)k * 512 + tid], a0);
      b0 = fmaf(xv1, Wv[(size_t)(k + 1) * 512 + tid], b0);
      a1 = fmaf(xv0, Wv[(size_t)k * 512 + tid + 256], a1);
      b1 = fmaf(xv1, Wv[(size_t)(k + 1) * 512 + tid + 256], b1);
    }
    V0ws[(size_t)row * 512 + tid] = a0 + b0;
    V0ws[(size_t)row * 512 + tid + 256] = a1 + b1;
  }
  if (tid < 128) {
    const float* W = (tid < 64) ? Wq : Wk;
    const int j = tid & 63;
    float a = 0, bpart = 0;
#pragma unroll 8
    for (int k = 0; k < 512; k += 2) {
      a = fmaf(x0f[k], W[(size_t)k * 64 + j], a);
      bpart = fmaf(x0f[k + 1], W[(size_t)(k + 1) * 64 + j], bpart);
    }
    QKws[(size_t)row * 128 + tid] = a + bpart;
  }
}

// ======== prep2: wsm + C-row + prc (128 small MFMA blocks) ========
// blocks 0..255: wsm; 256..259: C; 260..387: prc
__global__ __launch_bounds__(256) void prep2_k(
    const float* __restrict__ Xs, const float* __restrict__ QKws,
    const float* __restrict__ bq, float* __restrict__ Wws,
    const float* __restrict__ V0ws, const float* __restrict__ X0,
    const float* __restrict__ bv, const float* __restrict__ W1,
    const unsigned short* __restrict__ W1P,
    const float* __restrict__ gp, const float* __restrict__ b1,
    float* __restrict__ Pws, float* __restrict__ Rws, float* __restrict__ Cws) {
  const int tid = threadIdx.x;
  if (blockIdx.x < 256) {  // wsm
    const int b = blockIdx.x, t = tid;
    __shared__ float sv[256];
    __shared__ float scal[4];
    sv[t] = (t == 0) ? 1.0f : Xs[b * 255 + t - 1];
    __syncthreads();
    if (t == 0) {
      float al = 0, g2 = 0;
      for (int j = 0; j < 64; ++j) {
        al = fmaf(QKws[b * 128 + j], QKws[b * 128 + 64 + j], al);
        g2 = fmaf(bq[j], QKws[b * 128 + 64 + j], g2);
      }
      float mx = sv[0], mn = sv[0];
      for (int m2 = 1; m2 < 256; ++m2) { mx = fmaxf(mx, sv[m2]); mn = fminf(mn, sv[m2]); }
      scal[0] = al; scal[1] = g2; scal[2] = mx; scal[3] = mn;
    }
    __syncthreads();
    const float c = fmaf(scal[0], sv[tid], scal[1]);
    const float M = (c >= 0.f) ? c * scal[2] : c * scal[3];
    float Z = 0, Wm = 0;
    for (int m2 = 0; m2 < 256; ++m2) {
      const float e = __expf(fmaf(c, sv[m2], -M));
      Z += e;
      Wm = fmaf(sv[m2], e, Wm);
    }
    Wws[b * 256 + tid] = Wm / Z;
    return;
  }
  if (blockIdx.x < 260) {  // C[col] = g*(bv@W1)[col] + b1[col]
    const int col = (blockIdx.x - 256) * 256 + tid;
    float a = 0;
    for (int d = 0; d < 512; ++d) a = fmaf(bv[d], W1[(size_t)d * 1024 + col], a);
    Cws[col] = fmaf(gp[0], a, b1[col]);
    return;
  }
  // prc: {P,R} = {V0,X0} @ W1 (bf16 MFMA), 64x64 tile per block, 4 waves
  const int r = blockIdx.x - 260;        // 0..127
  const int pr = r >> 6;                 // 0: P(V0), 1: R(X0)
  const int rem = r & 63;
  const int mb = rem >> 4, nb = rem & 15;
  const float* srcA = pr ? X0 : V0ws;
  float* dst = pr ? Rws : Pws;
  const int lane = tid & 63, w = tid >> 6;
  const int la31 = lane & 31, hi = lane >> 5;
  const int rowbase = mb * 64 + (w >> 1) * 32;
  const int nbW = nb * 2 + (w & 1);
  const float* ar = srcA + (size_t)(rowbase + la31) * 512 + hi * 8;
  const unsigned short* pBW = W1P + ((size_t)nbW * 64 + lane) * 8;  // +16384/kg

  f32x16 acc;
#pragma unroll
  for (int i = 0; i < 16; ++i) acc[i] = 0.f;

  float4 fa[2][2];
  s16x8 bst[2];
  fa[0][0] = *(const float4*)(ar);
  fa[0][1] = *(const float4*)(ar + 4);
  bst[0] = *(const s16x8*)(pBW);
  pBW += 16384;

#pragma unroll 2
  for (int kg = 0; kg < 32; ++kg) {
    const int par = kg & 1;
    if (kg < 31) {
      fa[par ^ 1][0] = *(const float4*)(ar + (kg + 1) * 16);
      fa[par ^ 1][1] = *(const float4*)(ar + (kg + 1) * 16 + 4);
      bst[par ^ 1] = *(const s16x8*)(pBW);
      pBW += 16384;
    }
    union { s16x8 v; unsigned int u[4]; } t;
    const float4 a0 = fa[par][0], a1 = fa[par][1];
    t.u[0] = cvtpk(a0.x, a0.y);
    t.u[1] = cvtpk(a0.z, a0.w);
    t.u[2] = cvtpk(a1.x, a1.y);
    t.u[3] = cvtpk(a1.z, a1.w);
    acc = __builtin_amdgcn_mfma_f32_32x32x16_bf16(t.v, bst[par], acc, 0, 0, 0);
  }
#pragma unroll
  for (int reg = 0; reg < 16; ++reg) {
    const int rowl = (reg & 3) + 8 * (reg >> 2) + 4 * hi;
    dst[(size_t)(rowbase + rowl) * 1024 + nbW * 32 + la31] = acc[reg];
  }
}

// ======== fused: out = relu(relu(h1@W2+b2)@W3 + b3) ========
// BM=128, grid 512, 1024 thr (16 waves), phase A 1m x 16n (wave tile 128x32,
// acc 4x f32x16 = 64 AGPR), zero A/B duplication. A-tile gen'd once/block
// into LDS dbuf; B ring-of-4 depth-3 prefetch. In-loop barriers are SOFT
// (lgkmcnt-only, no vmcnt drain) so the B ring stays in flight (T4).
// LDS: At dbuf 2x32KB [0,65536) + PRC 12KB [65536,77824) phase A;
//      h2t 128KB [0,131072) phase B. 1 block/CU, 4 waves/SIMD.
__global__ __launch_bounds__(1024, 4) void fused_k(
    const float* __restrict__ Xs, const float* __restrict__ gp,
    const unsigned short* __restrict__ W2P,  // packed, 1MB
    const float* __restrict__ b2,
    const unsigned short* __restrict__ W3P,  // packed, 128KB
    const float* __restrict__ b3,
    const float* __restrict__ Cws, const float* __restrict__ Wws,
    const float* __restrict__ Pws, const float* __restrict__ Rws,
    float* __restrict__ out)  // [65536][128] f32
{
  __shared__ __align__(16) unsigned char sm[131072];
  unsigned short* smU = (unsigned short*)sm;
  float* PRC = (float*)(sm + 65536);  // P[1024] | R[1024] | C[1024]
  const int tid = threadIdx.x;
  const int lane = tid & 63, wid = tid >> 6;  // wid 0..15 = column group
  const int la31 = lane & 31, hi = lane >> 5;
  const int m0 = blockIdx.x * 128;
  const int b = blockIdx.x >> 1;
  const float g = gp[0];

  // A-generation: thread -> row rg 0..127; k-oct pair {ko, ko+8}, ko=tid>>7
  const int rg = tid & 127;
  const int ko = tid >> 7;  // wave-uniform (= wid>>1)
  const int tokg = (m0 & 255) + rg;
  const float gw = g * Wws[b * 256 + tokg];
  const float sr = (tokg == 0) ? 1.0f : Xs[b * 255 + tokg - 1];

  // PRC -> LDS: 3 elems/thread
#pragma unroll
  for (int i = 0; i < 3; ++i) {
    const int idx = i * 1024 + tid;
    float v;
    if (idx < 1024)      v = Pws[b * 1024 + idx];
    else if (idx < 2048) v = Rws[b * 1024 + (idx - 1024)];
    else                 v = Cws[idx - 2048];
    PRC[idx] = v;
  }

  // generate A-tile for `step` (128 rows x BK=128) into buffer `buf`
  auto gen = [&](int buf, int step) {
#pragma unroll
    for (int gsub = 0; gsub < 2; ++gsub) {
      const int s = gsub * 8 + ko;               // k-oct 0..15
      const int kb = step * 128 + s * 8;
      float e[8];
#pragma unroll
      for (int j = 0; j < 8; j += 4) {
        const float4 Pv = *(const float4*)(PRC + kb + j);          // broadcast
        const float4 Rv = *(const float4*)(PRC + 1024 + kb + j);
        const float4 Cv = *(const float4*)(PRC + 2048 + kb + j);
        e[j + 0] = fmaxf(fmaf(gw, Pv.x, fmaf(sr, Rv.x, Cv.x)), 0.f);
        e[j + 1] = fmaxf(fmaf(gw, Pv.y, fmaf(sr, Rv.y, Cv.y)), 0.f);
        e[j + 2] = fmaxf(fmaf(gw, Pv.z, fmaf(sr, Rv.z, Cv.z)), 0.f);
        e[j + 3] = fmaxf(fmaf(gw, Pv.w, fmaf(sr, Rv.w, Cv.w)), 0.f);
      }
      union { s16x8 v; unsigned int u[4]; } t0;
      t0.u[0] = cvtpk(e[0], e[1]);  t0.u[1] = cvtpk(e[2], e[3]);
      t0.u[2] = cvtpk(e[4], e[5]);  t0.u[3] = cvtpk(e[6], e[7]);
      *(s16x8*)(sm + buf * 32768 + (s * 128 + rg) * 16) = t0.v;
    }
  };

  f32x16 acc[4];
#pragma unroll
  for (int mf = 0; mf < 4; ++mf)
#pragma unroll
    for (int i = 0; i < 16; ++i) acc[mf][i] = 0.f;

  // B: ring-of-4 prefetch depth 3; wave wid owns frag nb=wid; +8192 elems/kg
  const unsigned short* pB = W2P + ((size_t)wid * 64 + lane) * 8;
  s16x8 bst[4];
#pragma unroll
  for (int d = 0; d < 3; ++d) {
    bst[d] = *(const s16x8*)(pB);
    pB += 8192;
  }

  softBarrier();       // PRC ready (B loads stay in flight)
  gen(0, 0);           // prologue A-tile

  // ---- phase A: 8 steps x 8 kg, soft barrier/step, B 3-deep in flight ----
  int kg = 0;
  for (int step = 0; step < 8; ++step) {
    softBarrier();     // buf[step&1] visible; other buf free to write
    if (step < 7) gen((step + 1) & 1, step + 1);
    const int abase = (step & 1) * 32768;
#pragma unroll
    for (int kgl = 0; kgl < 8; ++kgl, ++kg) {
      bst[(kg + 3) & 3] = *(const s16x8*)(pB);  // tail lands in W3P — safe
      pB += 8192;
      s16x8 af[4];
#pragma unroll
      for (int mf = 0; mf < 4; ++mf)
        af[mf] = *(const s16x8*)(sm + abase + ((kgl * 2 + hi) * 128 + mf * 32 + la31) * 16);
      const int cur = kg & 3;
      __builtin_amdgcn_s_setprio(1);
#pragma unroll
      for (int mf = 0; mf < 4; ++mf)
        acc[mf] = __builtin_amdgcn_mfma_f32_32x32x16_bf16(af[mf], bst[cur], acc[mf], 0, 0, 0);
      __builtin_amdgcn_s_setprio(0);
    }
  }
  softBarrier();  // last A-reads done before h2t overwrites LDS

  // ---- transition: h2 (bias+relu, bf16) -> h2t swizzled (128 rows) ----
  {
    const int col = wid * 32 + la31;
    const float bb = b2[col];
    const int sc = col >> 3, c7 = col & 7;
#pragma unroll
    for (int mf = 0; mf < 4; ++mf) {
#pragma unroll
      for (int reg = 0; reg < 16; ++reg) {
        const int row = mf * 32 + (reg & 3) + 8 * (reg >> 2) + 4 * hi;
        const int sp = (sc & 56) | ((sc ^ row) & 7);
        smU[row * 512 + sp * 8 + c7] = f2bfu(fmaxf(acc[mf][reg] + bb, 0.f));
      }
    }
  }
  softBarrier();  // h2t ready

  // ---- phase B: out 128x128 = relu(h2t @ W3 + b3); 16 waves 4m x 4n ----
  const int wr = wid >> 2, wc = wid & 3;
  f32x16 acc2;
#pragma unroll
  for (int i = 0; i < 16; ++i) acc2[i] = 0.f;

  const unsigned short* pW = W3P + ((size_t)wc * 64 + lane) * 8;  // +2048/kg
  s16x8 wst[4];
#pragma unroll
  for (int d = 0; d < 3; ++d) {
    wst[d] = *(const s16x8*)(pW);
    pW += 2048;
  }
#pragma unroll 4
  for (int kg2 = 0; kg2 < 32; ++kg2) {
    wst[(kg2 + 3) & 3] = *(const s16x8*)(pW);  // tail lands in V0ws — safe
    pW += 2048;
    const int s = kg2 * 2 + hi;
    const int row = wr * 32 + la31;
    const int sp = (s & 56) | ((s ^ row) & 7);
    const s16x8 afh = *(const s16x8*)(&sm[row * 1024 + (sp << 4)]);
    __builtin_amdgcn_s_setprio(1);
    acc2 = __builtin_amdgcn_mfma_f32_32x32x16_bf16(afh, wst[kg2 & 3], acc2, 0, 0, 0);
    __builtin_amdgcn_s_setprio(0);
  }

  // ---- epilogue: direct coalesced f32 stores ----
  {
    const int cB = wc * 32 + la31;
    const float b3v = b3[cB];
#pragma unroll
    for (int reg = 0; reg < 16; ++reg) {
      const int row = m0 + wr * 32 + (reg & 3) + 8 * (reg >> 2) + 4 * hi;
      out[(size_t)row * 128 + cB] = fmaxf(acc2[reg] + b3v, 0.f);
    }
  }
}

extern "C" void kernel_launch(void* const* d_in, const int* in_sizes, int n_in,
                              void* d_out, int out_size, void* d_ws, size_t ws_size,
                              hipStream_t stream) {
  const float* X0 = (const float*)d_in[0];
  const float* Xs = (const float*)d_in[1];
  const float* Wq = (const float*)d_in[2];
  const float* bq = (const float*)d_in[3];
  const float* Wk = (const float*)d_in[4];
  const float* bk = (const float*)d_in[5];
  const float* Wv = (const float*)d_in[6];
  const float* bv = (const float*)d_in[7];
  const float* gp = (const float*)d_in[8];
  const float* W1 = (const float*)d_in[9];
  const float* b1 = (const float*)d_in[10];
  const float* W2 = (const float*)d_in[11];
  const float* b2 = (const float*)d_in[12];
  const float* W3 = (const float*)d_in[13];
  const float* b3 = (const float*)d_in[14];

  char* ws = (char*)d_ws;
  float* Cws = (float*)(ws);                              //   4 KB
  float* Wws = (float*)(ws + 4096);                       // 256 KB
  float* Pws = (float*)(ws + 266240);                     //   1 MB
  float* Rws = (float*)(ws + 1314816);                    //   1 MB
  unsigned short* W2P = (unsigned short*)(ws + 2363392);  //   1 MB (packed bf16)
  unsigned short* W3P = (unsigned short*)(ws + 3411968);  // 128 KB (packed bf16)
  float* V0ws = (float*)(ws + 3543040);                   // 512 KB
  float* QKws = (float*)(ws + 4067328);                   // 128 KB
  unsigned short* W1P = (unsigned short*)(ws + 4198400);  //   1 MB (packed bf16)
  float* out = (float*)d_out;

  hipLaunchKernelGGL(prep1_k, dim3(320), dim3(256), 0, stream,
                     W2, W3, W1, W2P, W3P, W1P, X0, Wv, Wq, Wk, V0ws, QKws);
  hipLaunchKernelGGL(prep2_k, dim3(388), dim3(256), 0, stream,
                     Xs, QKws, bq, Wws, V0ws, X0, bv, W1, W1P, gp, b1, Pws, Rws, Cws);
  hipLaunchKernelGGL(fused_k, dim3(512), dim3(1024), 0, stream,
                     Xs, gp, W2P, b2, W3P, b3, Cws, Wws, Pws, Rws, out);
}